// Round 1
// baseline (3416.907 us; speedup 1.0000x reference)
//
#include <hip/hip_runtime.h>
#include <cstdint>
#include <cstddef>

// Problem constants
#define B_ 2
#define S_ 1024
#define D_ 1024
#define H_ 16
#define DK_ 64
#define DH_ 4096
#define L_ 8
#define V_ 256
#define M_ROWS 2048  // B_*S_

typedef unsigned short u16;
typedef __bf16 bf16x8 __attribute__((ext_vector_type(8)));
typedef float f32x4 __attribute__((ext_vector_type(4)));

__device__ __forceinline__ u16 f2b(float f) {
  union { float f; uint32_t u; } v; v.f = f;
  uint32_t u = v.u;
  return (u16)((u + 0x7FFFu + ((u >> 16) & 1u)) >> 16);
}
__device__ __forceinline__ float b2f(u16 h) {
  union { uint32_t u; float f; } v; v.u = ((uint32_t)h) << 16;
  return v.f;
}

// ---------------- embedding: x = emb[tok] + pos ----------------
__global__ void embed_kernel(const int* __restrict__ tokens, const float* __restrict__ emb,
                             const float* __restrict__ pos, float* __restrict__ xf,
                             u16* __restrict__ xb) {
  int row = blockIdx.x;            // 0..2047 (b*1024+s)
  int s = row & (S_ - 1);
  int tok = tokens[row];
  const float* e = emb + (size_t)tok * D_;
  const float* p = pos + (size_t)s * D_;
#pragma unroll
  for (int i = 0; i < D_ / 256; i++) {
    int d = threadIdx.x + i * 256;
    float v = e[d] + p[d];
    xf[(size_t)row * D_ + d] = v;
    xb[(size_t)row * D_ + d] = f2b(v);
  }
}

// ---------------- transpose + fp32->bf16 convert: Wt[n][k] = W[k][n] ----------------
__global__ void convT_kernel(const float* __restrict__ W, u16* __restrict__ Wt, int K, int N) {
  __shared__ float tile[32][33];
  int n0 = blockIdx.x * 32, k0 = blockIdx.y * 32;
  int tx = threadIdx.x & 31, ty = threadIdx.x >> 5;  // ty 0..7
#pragma unroll
  for (int i = 0; i < 4; i++) {
    int kr = ty + i * 8;
    tile[kr][tx] = W[(size_t)(k0 + kr) * N + n0 + tx];
  }
  __syncthreads();
#pragma unroll
  for (int i = 0; i < 4; i++) {
    int nr = ty + i * 8;
    Wt[(size_t)(n0 + nr) * K + k0 + tx] = f2b(tile[tx][nr]);
  }
}

// ---------------- masked softmax over scores rows (in place, bf16) ----------------
__global__ void softmax_kernel(u16* __restrict__ sc) {
  int row = blockIdx.x * 4 + (threadIdx.x >> 6);  // 0..32767 = z*1024 + qi
  int lane = threadIdx.x & 63;
  int z = row >> 10;
  int qi = row & 1023;
  u16* p = sc + (size_t)z * (S_ * S_) + (size_t)qi * S_;
  int rowEnd = ((qi >> 7) + 1) << 7;  // cols [0, rowEnd) exist (written by scores GEMM)
  const float scale = 0.125f;         // 1/sqrt(DK)
  float vals[16];
  float mx = -1e30f;
#pragma unroll
  for (int it = 0; it < 16; it++) {
    int j = lane + (it << 6);
    float v = (j <= qi) ? b2f(p[j]) * scale : -1e30f;
    vals[it] = v;
    mx = fmaxf(mx, v);
  }
#pragma unroll
  for (int o = 32; o > 0; o >>= 1) mx = fmaxf(mx, __shfl_xor(mx, o, 64));
  float sum = 0.f;
#pragma unroll
  for (int it = 0; it < 16; it++) {
    float e = (vals[it] > -1e29f) ? __expf(vals[it] - mx) : 0.f;
    vals[it] = e;
    sum += e;
  }
#pragma unroll
  for (int o = 32; o > 0; o >>= 1) sum += __shfl_xor(sum, o, 64);
  float inv = 1.f / sum;
#pragma unroll
  for (int it = 0; it < 16; it++) {
    int j = lane + (it << 6);
    if (j < rowEnd) p[j] = f2b(vals[it] * inv);
  }
}

// ---------------- generic MFMA GEMM: C = A @ Bt^T (+bias, +resid, gelu) ----------------
// A: [M,K] row-major bf16 (ldA). Bt: [N,K] row-major bf16 (ldB) (i.e. B transposed).
// Tile 128x128, BK=64, 256 threads = 4 waves, each wave 64x64 via 4x4 MFMA 16x16x32.
#define BM 128
#define BN 128
#define BK 64
#define LDSK (BK + 8)

enum { M_PLAIN = 0, M_QKV = 1, M_SCORES = 2, M_PV = 3 };

template <int MODE, bool BIAS, bool GELU, bool RESID, bool WF32, bool WBF16>
__global__ __launch_bounds__(256, 2) void gemm_kernel(
    const u16* __restrict__ Abase, const u16* __restrict__ Bbase,
    const float* __restrict__ bias0, const float* __restrict__ bias1,
    const float* __restrict__ bias2, const float* __restrict__ resid,
    float* __restrict__ Cf, u16* __restrict__ Cb, u16* __restrict__ Cb2,
    int M, int N, int K, int ldA, int ldB, int ldC) {
  int bn = blockIdx.x, bm = blockIdx.y, z = blockIdx.z;
  if (MODE == M_SCORES && bn > bm) return;  // fully masked tile

  const u16* A = Abase;
  const u16* Bt = Bbase;
  const float* bias = bias0;
  u16* cb = Cb;
  float* cf = Cf;
  int Keff = K;

  if (MODE == M_QKV) {
    Bt = Bbase + (size_t)z * (D_ * H_ * DK_);
    bias = (z == 0) ? bias0 : (z == 1) ? bias1 : bias2;
    cb = Cb + (size_t)z * (M_ROWS * 1024);  // z<2 only (z==2 uses Cb2 vtrans)
  } else if (MODE == M_SCORES) {
    int b = z >> 4, h = z & 15;
    A = Abase + (size_t)b * (S_ * D_) + h * DK_;
    Bt = Bbase + (size_t)b * (S_ * D_) + h * DK_;
    cb = Cb + (size_t)z * (S_ * S_);
  } else if (MODE == M_PV) {
    int b = z >> 4, h = z & 15;
    A = Abase + (size_t)z * (S_ * S_);
    Bt = Bbase + (size_t)z * (DK_ * S_);
    cb = Cb + (size_t)b * (S_ * D_) + h * DK_;
    Keff = min(K, (bm + 1) * BM);  // causal: P zero beyond this
  }

  int tid = threadIdx.x;
  int lane = tid & 63, l16 = lane & 15, quad = lane >> 4;
  int w = tid >> 6, wm = w >> 1, wn = w & 1;
  int m0 = bm * BM, n0 = bn * BN;

  __shared__ u16 sA[BM][LDSK];
  __shared__ u16 sB[BN][LDSK];

  f32x4 acc[4][4];
#pragma unroll
  for (int i = 0; i < 4; i++)
#pragma unroll
    for (int j = 0; j < 4; j++) {
      f32x4 zv = {0.f, 0.f, 0.f, 0.f};
      acc[i][j] = zv;
    }

  int r0 = tid >> 3;          // 0..31
  int c8 = (tid & 7) << 3;    // 0..56

  for (int k0 = 0; k0 < Keff; k0 += BK) {
#pragma unroll
    for (int i = 0; i < 4; i++) {
      int row = r0 + i * 32;
      *(uint4*)&sA[row][c8] =
          *(const uint4*)(A + (size_t)(m0 + row) * ldA + k0 + c8);
    }
#pragma unroll
    for (int i = 0; i < 4; i++) {
      int row = r0 + i * 32;
      uint4 val = make_uint4(0u, 0u, 0u, 0u);
      if (n0 + row < N) val = *(const uint4*)(Bt + (size_t)(n0 + row) * ldB + k0 + c8);
      *(uint4*)&sB[row][c8] = val;
    }
    __syncthreads();
#pragma unroll
    for (int kk = 0; kk < BK / 32; kk++) {
      bf16x8 af[4], bfr[4];
      int kb = kk * 32 + quad * 8;
#pragma unroll
      for (int mi = 0; mi < 4; mi++)
        af[mi] = *(const bf16x8*)&sA[wm * 64 + mi * 16 + l16][kb];
#pragma unroll
      for (int ni = 0; ni < 4; ni++)
        bfr[ni] = *(const bf16x8*)&sB[wn * 64 + ni * 16 + l16][kb];
#pragma unroll
      for (int mi = 0; mi < 4; mi++)
#pragma unroll
        for (int ni = 0; ni < 4; ni++)
          acc[mi][ni] = __builtin_amdgcn_mfma_f32_16x16x32_bf16(af[mi], bfr[ni],
                                                                acc[mi][ni], 0, 0, 0);
    }
    __syncthreads();
  }

  // epilogue: D lane map col = l16, row = quad*4 + r (verified m89/m91)
  bool vtrans = (MODE == M_QKV) && (z == 2);
#pragma unroll
  for (int mi = 0; mi < 4; mi++) {
#pragma unroll
    for (int ni = 0; ni < 4; ni++) {
      int col = n0 + wn * 64 + ni * 16 + l16;
      if (col >= N) continue;
      float bv = BIAS ? bias[col] : 0.f;
#pragma unroll
      for (int r = 0; r < 4; r++) {
        int row = m0 + wm * 64 + mi * 16 + quad * 4 + r;
        float v = acc[mi][ni][r] + bv;
        if (RESID) v += resid[(size_t)row * ldC + col];
        if (GELU) v = 0.5f * v * (1.f + erff(v * 0.70710678118f));
        if (WF32) cf[(size_t)row * ldC + col] = v;
        if (WBF16) {
          if (vtrans) {
            // write V transposed per (b,h): vT[((b*H+h)*DV + d)*S + s]
            int b = row >> 10, s = row & 1023, h = col >> 6, d = col & 63;
            Cb2[((size_t)((b * H_ + h) * DK_ + d)) * S_ + s] = f2b(v);
          } else {
            cb[(size_t)row * ldC + col] = f2b(v);
          }
        }
      }
    }
  }
}

// ---------------- host-side orchestration ----------------
extern "C" void kernel_launch(void* const* d_in, const int* in_sizes, int n_in,
                              void* d_out, int out_size, void* d_ws, size_t ws_size,
                              hipStream_t stream) {
  const int*   tokens = (const int*)d_in[0];
  const float* emb = (const float*)d_in[1];
  const float* pos = (const float*)d_in[2];
  const float* Wq  = (const float*)d_in[3];
  const float* bq  = (const float*)d_in[4];
  const float* Wk  = (const float*)d_in[5];
  const float* bk  = (const float*)d_in[6];
  const float* Wv  = (const float*)d_in[7];
  const float* bv  = (const float*)d_in[8];
  const float* Wo  = (const float*)d_in[9];
  const float* W1  = (const float*)d_in[10];
  const float* b1  = (const float*)d_in[11];
  const float* W2  = (const float*)d_in[12];
  const float* b2  = (const float*)d_in[13];
  const float* Wr  = (const float*)d_in[14];
  const float* br  = (const float*)d_in[15];
  float* out = (float*)d_out;

  char* ws = (char*)d_ws;
  size_t off = 0;
  auto alloc = [&](size_t bytes) {
    char* p = ws + off;
    off += (bytes + 255) & ~(size_t)255;
    return p;
  };
  float* xf  = (float*)alloc((size_t)M_ROWS * 1024 * 4);
  float* hf  = (float*)alloc((size_t)M_ROWS * 1024 * 4);
  u16*  xb   = (u16*)alloc((size_t)M_ROWS * 1024 * 2);
  u16*  hb   = (u16*)alloc((size_t)M_ROWS * 1024 * 2);
  u16*  qkb  = (u16*)alloc((size_t)2 * M_ROWS * 1024 * 2);  // q then k
  u16*  vT   = (u16*)alloc((size_t)M_ROWS * 1024 * 2);
  u16*  ob   = (u16*)alloc((size_t)M_ROWS * 1024 * 2);
  u16*  tmid = (u16*)alloc((size_t)M_ROWS * DH_ * 2);
  u16*  sc   = (u16*)alloc((size_t)32 * 1024 * 1024 * 2);
  u16*  Wt   = (u16*)alloc((size_t)12 * 1024 * 1024 * 2);
  u16*  WrT  = (u16*)alloc((size_t)V_ * 1024 * 2);
  (void)ws_size; (void)in_sizes; (void)n_in; (void)out_size;

  u16* WqT = Wt;                              // [1024,1024] x3 contiguous (q,k,v)
  u16* WoT = Wt + (size_t)3 * 1024 * 1024;    // [1024,1024]
  u16* W1T = Wt + (size_t)4 * 1024 * 1024;    // [4096,1024]
  u16* W2T = Wt + (size_t)8 * 1024 * 1024;    // [1024,4096]

  embed_kernel<<<dim3(M_ROWS), 256, 0, stream>>>(tokens, emb, pos, xf, xb);

  for (int l = 0; l < L_; l++) {
    size_t w1M = (size_t)l * 1024 * 1024;
    size_t w4M = (size_t)l * 1024 * 4096;
    convT_kernel<<<dim3(32, 32), 256, 0, stream>>>(Wq + w1M, WqT, 1024, 1024);
    convT_kernel<<<dim3(32, 32), 256, 0, stream>>>(Wk + w1M, WqT + 1024 * 1024, 1024, 1024);
    convT_kernel<<<dim3(32, 32), 256, 0, stream>>>(Wv + w1M, WqT + 2 * 1024 * 1024, 1024, 1024);
    convT_kernel<<<dim3(32, 32), 256, 0, stream>>>(Wo + w1M, WoT, 1024, 1024);
    convT_kernel<<<dim3(128, 32), 256, 0, stream>>>(W1 + w4M, W1T, 1024, 4096);
    convT_kernel<<<dim3(32, 128), 256, 0, stream>>>(W2 + w4M, W2T, 4096, 1024);

    // QKV projections (z=0:q, 1:k, 2:v-transposed)
    gemm_kernel<M_QKV, true, false, false, false, true><<<dim3(8, 16, 3), 256, 0, stream>>>(
        xb, WqT, bq + l * 1024, bk + l * 1024, bv + l * 1024, nullptr,
        nullptr, qkb, vT, M_ROWS, 1024, 1024, 1024, 1024, 1024);
    // scores = q @ k^T (causal blocks only), bf16 out
    gemm_kernel<M_SCORES, false, false, false, false, true><<<dim3(8, 8, 32), 256, 0, stream>>>(
        qkb, qkb + (size_t)M_ROWS * 1024, nullptr, nullptr, nullptr, nullptr,
        nullptr, sc, nullptr, S_, S_, DK_, 1024, 1024, S_);
    softmax_kernel<<<dim3(8192), 256, 0, stream>>>(sc);
    // o = P @ v
    gemm_kernel<M_PV, false, false, false, false, true><<<dim3(1, 8, 32), 256, 0, stream>>>(
        sc, vT, nullptr, nullptr, nullptr, nullptr,
        nullptr, ob, nullptr, S_, DK_, S_, S_, S_, 1024);
    // h = x + o @ Wo   (f32 + bf16 outs)
    gemm_kernel<M_PLAIN, false, false, true, true, true><<<dim3(8, 16), 256, 0, stream>>>(
        ob, WoT, nullptr, nullptr, nullptr, xf,
        hf, hb, nullptr, M_ROWS, 1024, 1024, 1024, 1024, 1024);
    // t = gelu(h @ W1 + b1)
    gemm_kernel<M_PLAIN, true, true, false, false, true><<<dim3(32, 16), 256, 0, stream>>>(
        hb, W1T, b1 + l * DH_, nullptr, nullptr, nullptr,
        nullptr, tmid, nullptr, M_ROWS, DH_, 1024, 1024, 1024, DH_);
    // x = h + t @ W2 + b2  (f32 + bf16 outs)
    gemm_kernel<M_PLAIN, true, false, true, true, true><<<dim3(8, 16), 256, 0, stream>>>(
        tmid, W2T, b2 + l * 1024, nullptr, nullptr, hf,
        xf, xb, nullptr, M_ROWS, 1024, DH_, DH_, DH_, 1024);
  }

  convT_kernel<<<dim3(8, 32), 256, 0, stream>>>(Wr, WrT, 1024, V_);
  // logits = x @ Wr + br  (fp32 out)
  gemm_kernel<M_PLAIN, true, false, false, true, false><<<dim3(2, 16), 256, 0, stream>>>(
      xb, WrT, br, nullptr, nullptr, nullptr,
      out, nullptr, nullptr, M_ROWS, V_, 1024, 1024, 1024, V_);
}

// Round 2
// 1765.366 us; speedup vs baseline: 1.9355x; 1.9355x over previous
//
#include <hip/hip_runtime.h>
#include <cstdint>
#include <cstddef>

// Problem constants
#define B_ 2
#define S_ 1024
#define D_ 1024
#define H_ 16
#define DK_ 64
#define DH_ 4096
#define L_ 8
#define V_ 256
#define M_ROWS 2048  // B_*S_

typedef unsigned short u16;
typedef __bf16 bf16x8 __attribute__((ext_vector_type(8)));
typedef float f32x4 __attribute__((ext_vector_type(4)));

__device__ __forceinline__ u16 f2b(float f) {
  union { float f; uint32_t u; } v; v.f = f;
  uint32_t u = v.u;
  return (u16)((u + 0x7FFFu + ((u >> 16) & 1u)) >> 16);
}
__device__ __forceinline__ float b2f(u16 h) {
  union { uint32_t u; float f; } v; v.u = ((uint32_t)h) << 16;
  return v.f;
}

// async global->LDS, 16B per lane; LDS dest = wave-uniform base + lane*16
__device__ __forceinline__ void load16_lds(const void* g, void* l) {
  __builtin_amdgcn_global_load_lds(
      (const __attribute__((address_space(1))) unsigned int*)g,
      (__attribute__((address_space(3))) unsigned int*)l, 16, 0, 0);
}

// ---------------- embedding: x = emb[tok] + pos ----------------
__global__ void embed_kernel(const int* __restrict__ tokens, const float* __restrict__ emb,
                             const float* __restrict__ pos, float* __restrict__ xf,
                             u16* __restrict__ xb) {
  int row = blockIdx.x;
  int s = row & (S_ - 1);
  int tok = tokens[row];
  const float* e = emb + (size_t)tok * D_;
  const float* p = pos + (size_t)s * D_;
#pragma unroll
  for (int i = 0; i < D_ / 256; i++) {
    int d = threadIdx.x + i * 256;
    float v = e[d] + p[d];
    xf[(size_t)row * D_ + d] = v;
    xb[(size_t)row * D_ + d] = f2b(v);
  }
}

// ---------------- transpose + fp32->bf16: Wt[n][k] = W[k][n] ----------------
__global__ void convT_kernel(const float* __restrict__ W, u16* __restrict__ Wt, int K, int N) {
  __shared__ float tile[32][33];
  int n0 = blockIdx.x * 32, k0 = blockIdx.y * 32;
  int tx = threadIdx.x & 31, ty = threadIdx.x >> 5;
#pragma unroll
  for (int i = 0; i < 4; i++)
    tile[ty + i * 8][tx] = W[(size_t)(k0 + ty + i * 8) * N + n0 + tx];
  __syncthreads();
#pragma unroll
  for (int i = 0; i < 4; i++)
    Wt[(size_t)(n0 + ty + i * 8) * K + k0 + tx] = f2b(tile[tx][ty + i * 8]);
}

// One launch converting a whole layer's weights (Wq,Wk,Wv,Wo,W1,W2). 12288 tiles.
__global__ void convAll_kernel(const float* __restrict__ Wq, const float* __restrict__ Wk,
                               const float* __restrict__ Wv, const float* __restrict__ Wo,
                               const float* __restrict__ W1, const float* __restrict__ W2,
                               int l, u16* __restrict__ WqT, u16* __restrict__ WoT,
                               u16* __restrict__ W1T, u16* __restrict__ W2T) {
  int t = blockIdx.x;
  const float* src; u16* dst; int K, N, bx, by;
  if (t < 3072) {
    int which = t >> 10, t2 = t & 1023;
    src = (which == 0 ? Wq : which == 1 ? Wk : Wv) + (size_t)l * (1u << 20);
    dst = WqT + (size_t)which * (1u << 20);
    K = 1024; N = 1024; bx = t2 & 31; by = t2 >> 5;
  } else if (t < 4096) {
    int t2 = t - 3072;
    src = Wo + (size_t)l * (1u << 20); dst = WoT;
    K = 1024; N = 1024; bx = t2 & 31; by = t2 >> 5;
  } else if (t < 8192) {
    int t2 = t - 4096;
    src = W1 + (size_t)l * (4u << 20); dst = W1T;
    K = 1024; N = 4096; bx = t2 & 127; by = t2 >> 7;
  } else {
    int t2 = t - 8192;
    src = W2 + (size_t)l * (4u << 20); dst = W2T;
    K = 4096; N = 1024; bx = t2 & 31; by = t2 >> 5;
  }
  __shared__ float tile[32][33];
  int n0 = bx * 32, k0 = by * 32;
  int tx = threadIdx.x & 31, ty = threadIdx.x >> 5;
#pragma unroll
  for (int i = 0; i < 4; i++)
    tile[ty + i * 8][tx] = src[(size_t)(k0 + ty + i * 8) * N + n0 + tx];
  __syncthreads();
#pragma unroll
  for (int i = 0; i < 4; i++)
    dst[(size_t)(n0 + ty + i * 8) * K + k0 + tx] = f2b(tile[tx][ty + i * 8]);
}

// ---------------- fused flash attention ----------------
// grid (16 q-tiles, 32 b*h). Q-tile 64 rows; each of 4 waves owns 16 q-rows.
// qb/kb: [B*S][1024] (h*64+d cols). vT: [bh][64 d][1024 s]. ob: [B*S][1024].
__global__ __launch_bounds__(256, 2) void flash_kernel(
    const u16* __restrict__ qb, const u16* __restrict__ kb,
    const u16* __restrict__ vT, u16* __restrict__ ob) {
  int qt = (int)(gridDim.x - 1) - (int)blockIdx.x;  // descending work for balance
  int bh = blockIdx.y;
  int b = bh >> 4, h = bh & 15;
  int tid = threadIdx.x, lane = tid & 63, w = tid >> 6;
  int l16 = lane & 15, quad = lane >> 4;

  __shared__ u16 sQ[64][72];
  __shared__ u16 sK[128][72];
  __shared__ u16 sV[64][136];
  __shared__ u16 sP[4][16][136];

  {  // stage Q, pre-scaled by 1/sqrt(DK)=0.125 (exact in bf16)
    int row = tid >> 2;
    int c0 = (tid & 3) * 16;
    const u16* g = qb + ((size_t)(b * S_ + qt * 64 + row)) * 1024 + h * 64 + c0;
#pragma unroll
    for (int c = 0; c < 2; c++) {
      union { uint4 v; u16 h[8]; } u;
      u.v = *(const uint4*)(g + c * 8);
#pragma unroll
      for (int j = 0; j < 8; j++) u.h[j] = f2b(b2f(u.h[j]) * 0.125f);
      *(uint4*)&sQ[row][c0 + c * 8] = u.v;
    }
  }

  f32x4 accO[4];
#pragma unroll
  for (int i = 0; i < 4; i++) { f32x4 z = {0.f, 0.f, 0.f, 0.f}; accO[i] = z; }
  float mrow[4], lrow[4];
#pragma unroll
  for (int r = 0; r < 4; r++) { mrow[r] = -1e30f; lrow[r] = 0.f; }

  int ktmax = qt >> 1;
  for (int kt = 0; kt <= ktmax; kt++) {
    {  // stage K tile [128 kv][64 d]
      int row = tid >> 1, c0 = (tid & 1) * 32;
      const u16* g = kb + ((size_t)(b * S_ + kt * 128 + row)) * 1024 + h * 64;
#pragma unroll
      for (int c = 0; c < 4; c++)
        *(uint4*)&sK[row][c0 + c * 8] = *(const uint4*)(g + c0 + c * 8);
      // stage V^T tile [64 d][128 kv]
      int rv = tid >> 2, cv0 = (tid & 3) * 32;
      const u16* gv = vT + ((size_t)(bh * 64 + rv)) * 1024 + kt * 128;
#pragma unroll
      for (int c = 0; c < 4; c++)
        *(uint4*)&sV[rv][cv0 + c * 8] = *(const uint4*)(gv + cv0 + c * 8);
    }
    __syncthreads();

    // S = Q @ K^T : wave rows [w*16, w*16+16), cols [0,128)
    f32x4 accS[8];
#pragma unroll
    for (int ni = 0; ni < 8; ni++) { f32x4 z = {0.f, 0.f, 0.f, 0.f}; accS[ni] = z; }
#pragma unroll
    for (int kk = 0; kk < 2; kk++) {
      bf16x8 a = *(const bf16x8*)&sQ[w * 16 + l16][kk * 32 + quad * 8];
#pragma unroll
      for (int ni = 0; ni < 8; ni++) {
        bf16x8 bb = *(const bf16x8*)&sK[ni * 16 + l16][kk * 32 + quad * 8];
        accS[ni] = __builtin_amdgcn_mfma_f32_16x16x32_bf16(a, bb, accS[ni], 0, 0, 0);
      }
    }
    int qw0 = qt * 64 + w * 16;
    if (kt * 128 + 127 > qw0) {  // causal mask needed (wave-uniform branch)
#pragma unroll
      for (int ni = 0; ni < 8; ni++) {
        int kv = kt * 128 + ni * 16 + l16;
#pragma unroll
        for (int r = 0; r < 4; r++)
          if (kv > qw0 + quad * 4 + r) accS[ni][r] = -1e30f;
      }
    }
    // online softmax: row stats across ni (regs) then 16 lanes (same quad)
    float alpha[4];
#pragma unroll
    for (int r = 0; r < 4; r++) {
      float m = accS[0][r];
#pragma unroll
      for (int ni = 1; ni < 8; ni++) m = fmaxf(m, accS[ni][r]);
#pragma unroll
      for (int off = 1; off < 16; off <<= 1) m = fmaxf(m, __shfl_xor(m, off, 64));
      float mn = fmaxf(mrow[r], m);
      alpha[r] = __expf(mrow[r] - mn);
      mrow[r] = mn;
    }
    float sum[4] = {0.f, 0.f, 0.f, 0.f};
#pragma unroll
    for (int ni = 0; ni < 8; ni++) {
#pragma unroll
      for (int r = 0; r < 4; r++) {
        float p = __expf(accS[ni][r] - mrow[r]);
        sum[r] += p;
        sP[w][quad * 4 + r][ni * 16 + l16] = f2b(p);  // C-layout -> A-layout via LDS
      }
    }
#pragma unroll
    for (int r = 0; r < 4; r++) {
#pragma unroll
      for (int off = 1; off < 16; off <<= 1) sum[r] += __shfl_xor(sum[r], off, 64);
      lrow[r] = lrow[r] * alpha[r] + sum[r];
#pragma unroll
      for (int ni = 0; ni < 4; ni++) accO[ni][r] *= alpha[r];
    }
    __syncthreads();
    // O += P @ V : A from sP (q rows, kv contig), B from sV (d rows, kv contig)
#pragma unroll
    for (int kk2 = 0; kk2 < 4; kk2++) {
      bf16x8 a = *(const bf16x8*)&sP[w][l16][kk2 * 32 + quad * 8];
#pragma unroll
      for (int ni = 0; ni < 4; ni++) {
        bf16x8 bb = *(const bf16x8*)&sV[ni * 16 + l16][kk2 * 32 + quad * 8];
        accO[ni] = __builtin_amdgcn_mfma_f32_16x16x32_bf16(a, bb, accO[ni], 0, 0, 0);
      }
    }
    __syncthreads();
  }
  u16* orow = ob + ((size_t)(b * S_ + qt * 64 + w * 16 + quad * 4)) * 1024 + h * 64;
#pragma unroll
  for (int r = 0; r < 4; r++) {
    float inv = 1.0f / lrow[r];
#pragma unroll
    for (int ni = 0; ni < 4; ni++)
      orow[(size_t)r * 1024 + ni * 16 + l16] = f2b(accO[ni][r] * inv);
  }
}

// ---------------- MFMA GEMM, m97-style global_load_lds staging + XOR swizzle ----
// C = A @ Bt^T. A [M,K] bf16, Bt [N,K] bf16. Tile 128x128, BK=64, 4 waves.
// LDS chunk (16B) at phys slot p of row r holds logical chunk p ^ (r&7):
// staging permutes the global source chunk per lane (dest is lane-linear),
// readers un-swizzle -> conflict-free ds_read_b128 without padding.
enum { M_PLAIN = 0, M_QKV = 1 };

template <int MODE, bool BIAS, bool GELU, bool RESID, bool WF32, bool WBF16>
__global__ __launch_bounds__(256, 2) void gemm_kernel(
    const u16* __restrict__ A, const u16* __restrict__ Bbase,
    const float* __restrict__ bias0, const float* __restrict__ bias1,
    const float* __restrict__ bias2, const float* __restrict__ resid,
    float* __restrict__ Cf, u16* __restrict__ Cb, u16* __restrict__ vTout,
    int M, int N, int K, int ldA, int ldB, int ldC) {
  int bn = blockIdx.x, bm = blockIdx.y, z = blockIdx.z;
  const u16* Bt = Bbase;
  const float* bias = bias0;
  u16* cb = Cb;
  if (MODE == M_QKV) {
    Bt = Bbase + (size_t)z * (1u << 20);
    bias = (z == 0) ? bias0 : (z == 1) ? bias1 : bias2;
    cb = Cb + (size_t)z * ((size_t)M_ROWS * 1024);
  }
  int tid = threadIdx.x;
  int lane = tid & 63, w = tid >> 6;
  int l16 = lane & 15, quad = lane >> 4;
  int wm = w >> 1, wn = w & 1;
  int m0 = bm * 128, n0 = bn * 128;
  int rsub = lane >> 3, csw = lane & 7;

  __shared__ u16 smem[16384];  // sA [128][64] @0, sB [128][64] @8192

  f32x4 acc[4][4];
#pragma unroll
  for (int i = 0; i < 4; i++)
#pragma unroll
    for (int j = 0; j < 4; j++) { f32x4 zv = {0.f, 0.f, 0.f, 0.f}; acc[i][j] = zv; }

  int rowA = w * 32 + rsub;  // +i*8; (rowA+i*8)&7 == rowA&7
  int swsrc = (csw ^ (rowA & 7)) << 3;
  const u16* gA = A + (size_t)(m0 + rowA) * ldA + swsrc;
  const u16* gB = Bt + (size_t)(n0 + rowA) * ldB + swsrc;
  int swz = l16 & 7;

  for (int k0 = 0; k0 < K; k0 += 64) {
#pragma unroll
    for (int i = 0; i < 4; i++) {
      load16_lds(gA + (size_t)(i * 8) * ldA + k0, &smem[(w * 32 + i * 8) * 64]);
      load16_lds(gB + (size_t)(i * 8) * ldB + k0, &smem[8192 + (w * 32 + i * 8) * 64]);
    }
    __syncthreads();
#pragma unroll
    for (int kk = 0; kk < 2; kk++) {
      bf16x8 af[4], bfr[4];
#pragma unroll
      for (int mi = 0; mi < 4; mi++)
        af[mi] = *(const bf16x8*)&smem[(wm * 64 + mi * 16 + l16) * 64 +
                                       (((kk * 4 + quad) ^ swz) << 3)];
#pragma unroll
      for (int ni = 0; ni < 4; ni++)
        bfr[ni] = *(const bf16x8*)&smem[8192 + (wn * 64 + ni * 16 + l16) * 64 +
                                        (((kk * 4 + quad) ^ swz) << 3)];
#pragma unroll
      for (int mi = 0; mi < 4; mi++)
#pragma unroll
        for (int ni = 0; ni < 4; ni++)
          acc[mi][ni] = __builtin_amdgcn_mfma_f32_16x16x32_bf16(af[mi], bfr[ni],
                                                                acc[mi][ni], 0, 0, 0);
    }
    __syncthreads();
  }

  if (MODE == M_QKV && z == 2) {
    // V output: transpose tile through LDS (chunk-swizzled), write vT coalesced.
#pragma unroll
    for (int mi = 0; mi < 4; mi++) {
      int sl = wm * 64 + mi * 16 + quad * 4;  // tile row (s), 4 consecutive
#pragma unroll
      for (int ni = 0; ni < 4; ni++) {
        int dl = wn * 64 + ni * 16 + l16;     // tile col (d-composite)
        float bv = bias[n0 + dl];
        union { u16 h[4]; uint2 u; } pk;
#pragma unroll
        for (int r = 0; r < 4; r++) pk.h[r] = f2b(acc[mi][ni][r] + bv);
        int phys = ((((sl >> 3) ^ (dl & 7)) << 3) | (sl & 7));
        *(uint2*)&smem[dl * 128 + phys] = pk.u;
      }
    }
    __syncthreads();
    {
      int drow = tid >> 1;           // 0..127 (tile col = d-composite)
      int b = m0 >> 10;
      int gcol = n0 + drow;
      u16* dst = vTout + ((size_t)((b * 16 + (gcol >> 6)) * 64 + (gcol & 63))) * 1024 +
                 (m0 & 1023);
#pragma unroll
      for (int i = 0; i < 8; i++) {
        int sc = (tid & 1) * 8 + i;  // s-chunk 0..15
        int phys = sc ^ (drow & 7);
        *(uint4*)(dst + sc * 8) = *(const uint4*)&smem[drow * 128 + phys * 8];
      }
    }
    return;
  }

  // normal epilogue: C/D map col=l16, row=quad*4+r
#pragma unroll
  for (int mi = 0; mi < 4; mi++)
#pragma unroll
    for (int ni = 0; ni < 4; ni++) {
      int col = n0 + wn * 64 + ni * 16 + l16;
      float bv = BIAS ? bias[col] : 0.f;
#pragma unroll
      for (int r = 0; r < 4; r++) {
        int row = m0 + wm * 64 + mi * 16 + quad * 4 + r;
        float v = acc[mi][ni][r] + bv;
        if (RESID) v += resid[(size_t)row * ldC + col];
        if (GELU) v = 0.5f * v * (1.f + erff(v * 0.70710678118f));
        if (WF32) Cf[(size_t)row * ldC + col] = v;
        if (WBF16) cb[(size_t)row * ldC + col] = f2b(v);
      }
    }
}

// ---------------- host-side orchestration ----------------
extern "C" void kernel_launch(void* const* d_in, const int* in_sizes, int n_in,
                              void* d_out, int out_size, void* d_ws, size_t ws_size,
                              hipStream_t stream) {
  const int*   tokens = (const int*)d_in[0];
  const float* emb = (const float*)d_in[1];
  const float* pos = (const float*)d_in[2];
  const float* Wq  = (const float*)d_in[3];
  const float* bq  = (const float*)d_in[4];
  const float* Wk  = (const float*)d_in[5];
  const float* bk  = (const float*)d_in[6];
  const float* Wv  = (const float*)d_in[7];
  const float* bv  = (const float*)d_in[8];
  const float* Wo  = (const float*)d_in[9];
  const float* W1  = (const float*)d_in[10];
  const float* b1  = (const float*)d_in[11];
  const float* W2  = (const float*)d_in[12];
  const float* b2  = (const float*)d_in[13];
  const float* Wr  = (const float*)d_in[14];
  const float* br  = (const float*)d_in[15];
  float* out = (float*)d_out;

  char* ws = (char*)d_ws;
  size_t off = 0;
  auto alloc = [&](size_t bytes) {
    char* p = ws + off;
    off += (bytes + 255) & ~(size_t)255;
    return p;
  };
  float* xf  = (float*)alloc((size_t)M_ROWS * 1024 * 4);
  float* hf  = (float*)alloc((size_t)M_ROWS * 1024 * 4);
  u16*  xb   = (u16*)alloc((size_t)M_ROWS * 1024 * 2);
  u16*  hb   = (u16*)alloc((size_t)M_ROWS * 1024 * 2);
  u16*  qkb  = (u16*)alloc((size_t)2 * M_ROWS * 1024 * 2);  // q then k
  u16*  vT   = (u16*)alloc((size_t)M_ROWS * 1024 * 2);
  u16*  ob   = (u16*)alloc((size_t)M_ROWS * 1024 * 2);
  u16*  tmid = (u16*)alloc((size_t)M_ROWS * DH_ * 2);
  u16*  Wt   = (u16*)alloc((size_t)12 * 1024 * 1024 * 2);
  u16*  WrT  = (u16*)alloc((size_t)V_ * 1024 * 2);
  (void)ws_size; (void)in_sizes; (void)n_in; (void)out_size;

  u16* WqT = Wt;                              // [1024,1024] x3 (q,k,v)
  u16* WoT = Wt + (size_t)3 * 1024 * 1024;
  u16* W1T = Wt + (size_t)4 * 1024 * 1024;    // [4096,1024]
  u16* W2T = Wt + (size_t)8 * 1024 * 1024;    // [1024,4096]

  embed_kernel<<<dim3(M_ROWS), 256, 0, stream>>>(tokens, emb, pos, xf, xb);

  for (int l = 0; l < L_; l++) {
    convAll_kernel<<<dim3(12288), 256, 0, stream>>>(Wq, Wk, Wv, Wo, W1, W2, l,
                                                    WqT, WoT, W1T, W2T);
    // QKV projections (z=0:q, 1:k, 2:v written transposed into vT)
    gemm_kernel<M_QKV, true, false, false, false, true><<<dim3(8, 16, 3), 256, 0, stream>>>(
        xb, WqT, bq + l * 1024, bk + l * 1024, bv + l * 1024, nullptr,
        nullptr, qkb, vT, M_ROWS, 1024, 1024, 1024, 1024, 1024);
    // fused flash attention
    flash_kernel<<<dim3(16, 32), 256, 0, stream>>>(qkb, qkb + (size_t)M_ROWS * 1024, vT, ob);
    // h = x + o @ Wo
    gemm_kernel<M_PLAIN, false, false, true, true, true><<<dim3(8, 16), 256, 0, stream>>>(
        ob, WoT, nullptr, nullptr, nullptr, xf,
        hf, hb, nullptr, M_ROWS, 1024, 1024, 1024, 1024, 1024);
    // t = gelu(h @ W1 + b1)
    gemm_kernel<M_PLAIN, true, true, false, false, true><<<dim3(32, 16), 256, 0, stream>>>(
        hb, W1T, b1 + l * DH_, nullptr, nullptr, nullptr,
        nullptr, tmid, nullptr, M_ROWS, DH_, 1024, 1024, 1024, DH_);
    // x = h + t @ W2 + b2
    gemm_kernel<M_PLAIN, true, false, true, true, true><<<dim3(8, 16), 256, 0, stream>>>(
        tmid, W2T, b2 + l * 1024, nullptr, nullptr, hf,
        xf, xb, nullptr, M_ROWS, 1024, DH_, DH_, DH_, 1024);
  }

  convT_kernel<<<dim3(8, 32), 256, 0, stream>>>(Wr, WrT, 1024, V_);
  // logits = x @ Wr + br
  gemm_kernel<M_PLAIN, true, false, false, true, false><<<dim3(2, 16), 256, 0, stream>>>(
      xb, WrT, br, nullptr, nullptr, nullptr,
      out, nullptr, nullptr, M_ROWS, V_, 1024, 1024, 1024, V_);
}

// Round 3
// 1685.905 us; speedup vs baseline: 2.0267x; 1.0471x over previous
//
#include <hip/hip_runtime.h>
#include <cstdint>
#include <cstddef>

// Problem constants
#define B_ 2
#define S_ 1024
#define D_ 1024
#define H_ 16
#define DK_ 64
#define DH_ 4096
#define L_ 8
#define V_ 256
#define M_ROWS 2048  // B_*S_

typedef unsigned short u16;
typedef __bf16 bf16x8 __attribute__((ext_vector_type(8)));
typedef float f32x4 __attribute__((ext_vector_type(4)));

__device__ __forceinline__ u16 f2b(float f) {
  union { float f; uint32_t u; } v; v.f = f;
  uint32_t u = v.u;
  return (u16)((u + 0x7FFFu + ((u >> 16) & 1u)) >> 16);
}
__device__ __forceinline__ float b2f(u16 h) {
  union { uint32_t u; float f; } v; v.u = ((uint32_t)h) << 16;
  return v.f;
}

// async global->LDS, 16B per lane; LDS dest = wave-uniform base + lane*16
__device__ __forceinline__ void load16_lds(const void* g, void* l) {
  __builtin_amdgcn_global_load_lds(
      (const __attribute__((address_space(1))) unsigned int*)g,
      (__attribute__((address_space(3))) unsigned int*)l, 16, 0, 0);
}

// ---------------- embedding: x = emb[tok] + pos ----------------
__global__ void embed_kernel(const int* __restrict__ tokens, const float* __restrict__ emb,
                             const float* __restrict__ pos, float* __restrict__ xf,
                             u16* __restrict__ xb) {
  int row = blockIdx.x;
  int s = row & (S_ - 1);
  int tok = tokens[row];
  const float* e = emb + (size_t)tok * D_;
  const float* p = pos + (size_t)s * D_;
#pragma unroll
  for (int i = 0; i < D_ / 256; i++) {
    int d = threadIdx.x + i * 256;
    float v = e[d] + p[d];
    xf[(size_t)row * D_ + d] = v;
    xb[(size_t)row * D_ + d] = f2b(v);
  }
}

// ---- one launch converting ALL layers' weights + Wr: Wt[n][k] = bf16(W[k][n]) ----
// per-layer slab (u16): WqT/WkT/WvT [3M] + WoT [1M] + W1T [4M] + W2T [4M] = 12M
__global__ void convAllLayers_kernel(const float* __restrict__ Wq, const float* __restrict__ Wk,
                                     const float* __restrict__ Wv, const float* __restrict__ Wo,
                                     const float* __restrict__ W1, const float* __restrict__ W2,
                                     const float* __restrict__ Wr,
                                     u16* __restrict__ Wt, u16* __restrict__ WrT) {
  int t = blockIdx.x;
  const float* src; u16* dst; int K, N, bx, by;
  if (t < 98304) {
    int l = t / 12288, s = t % 12288;
    u16* slab = Wt + (size_t)l * (12u << 20);
    if (s < 3072) {
      int which = s >> 10, t2 = s & 1023;
      src = (which == 0 ? Wq : which == 1 ? Wk : Wv) + (size_t)l * (1u << 20);
      dst = slab + (size_t)which * (1u << 20);
      K = 1024; N = 1024; bx = t2 & 31; by = t2 >> 5;
    } else if (s < 4096) {
      int t2 = s - 3072;
      src = Wo + (size_t)l * (1u << 20); dst = slab + (3u << 20);
      K = 1024; N = 1024; bx = t2 & 31; by = t2 >> 5;
    } else if (s < 8192) {
      int t2 = s - 4096;
      src = W1 + (size_t)l * (4u << 20); dst = slab + (4u << 20);
      K = 1024; N = 4096; bx = t2 & 127; by = t2 >> 7;
    } else {
      int t2 = s - 8192;
      src = W2 + (size_t)l * (4u << 20); dst = slab + (8u << 20);
      K = 4096; N = 1024; bx = t2 & 31; by = t2 >> 5;
    }
  } else {
    int t2 = t - 98304;  // Wr [1024,256] -> 8 x 32 tiles
    src = Wr; dst = WrT;
    K = 1024; N = 256; bx = t2 & 7; by = t2 >> 3;
  }
  __shared__ float tile[32][33];
  int n0 = bx * 32, k0 = by * 32;
  int tx = threadIdx.x & 31, ty = threadIdx.x >> 5;
#pragma unroll
  for (int i = 0; i < 4; i++)
    tile[ty + i * 8][tx] = src[(size_t)(k0 + ty + i * 8) * N + n0 + tx];
  __syncthreads();
#pragma unroll
  for (int i = 0; i < 4; i++)
    dst[(size_t)(n0 + ty + i * 8) * K + k0 + tx] = f2b(tile[tx][ty + i * 8]);
}

// ---------------- fused flash attention ----------------
// grid (16 q-tiles, 32 b*h). Q-tile 64 rows; each of 4 waves owns 16 q-rows.
__global__ __launch_bounds__(256, 2) void flash_kernel(
    const u16* __restrict__ qb, const u16* __restrict__ kb,
    const u16* __restrict__ vT, u16* __restrict__ ob) {
  int qt = (int)(gridDim.x - 1) - (int)blockIdx.x;  // descending work for balance
  int bh = blockIdx.y;
  int b = bh >> 4, h = bh & 15;
  int tid = threadIdx.x, lane = tid & 63, w = tid >> 6;
  int l16 = lane & 15, quad = lane >> 4;

  __shared__ u16 sQ[64][72];
  __shared__ u16 sK[128][72];
  __shared__ u16 sV[64][136];
  __shared__ u16 sP[4][16][136];

  {  // stage Q, pre-scaled by 1/sqrt(DK)=0.125 (exact in bf16)
    int row = tid >> 2;
    int c0 = (tid & 3) * 16;
    const u16* g = qb + ((size_t)(b * S_ + qt * 64 + row)) * 1024 + h * 64 + c0;
#pragma unroll
    for (int c = 0; c < 2; c++) {
      union { uint4 v; u16 h[8]; } u;
      u.v = *(const uint4*)(g + c * 8);
#pragma unroll
      for (int j = 0; j < 8; j++) u.h[j] = f2b(b2f(u.h[j]) * 0.125f);
      *(uint4*)&sQ[row][c0 + c * 8] = u.v;
    }
  }

  f32x4 accO[4];
#pragma unroll
  for (int i = 0; i < 4; i++) { f32x4 z = {0.f, 0.f, 0.f, 0.f}; accO[i] = z; }
  float mrow[4], lrow[4];
#pragma unroll
  for (int r = 0; r < 4; r++) { mrow[r] = -1e30f; lrow[r] = 0.f; }

  int ktmax = qt >> 1;
  for (int kt = 0; kt <= ktmax; kt++) {
    {  // stage K tile [128 kv][64 d] and V^T tile [64 d][128 kv]
      int row = tid >> 1, c0 = (tid & 1) * 32;
      const u16* g = kb + ((size_t)(b * S_ + kt * 128 + row)) * 1024 + h * 64;
#pragma unroll
      for (int c = 0; c < 4; c++)
        *(uint4*)&sK[row][c0 + c * 8] = *(const uint4*)(g + c0 + c * 8);
      int rv = tid >> 2, cv0 = (tid & 3) * 32;
      const u16* gv = vT + ((size_t)(bh * 64 + rv)) * 1024 + kt * 128;
#pragma unroll
      for (int c = 0; c < 4; c++)
        *(uint4*)&sV[rv][cv0 + c * 8] = *(const uint4*)(gv + cv0 + c * 8);
    }
    __syncthreads();

    // S = Q @ K^T
    f32x4 accS[8];
#pragma unroll
    for (int ni = 0; ni < 8; ni++) { f32x4 z = {0.f, 0.f, 0.f, 0.f}; accS[ni] = z; }
#pragma unroll
    for (int kk = 0; kk < 2; kk++) {
      bf16x8 a = *(const bf16x8*)&sQ[w * 16 + l16][kk * 32 + quad * 8];
#pragma unroll
      for (int ni = 0; ni < 8; ni++) {
        bf16x8 bb = *(const bf16x8*)&sK[ni * 16 + l16][kk * 32 + quad * 8];
        accS[ni] = __builtin_amdgcn_mfma_f32_16x16x32_bf16(a, bb, accS[ni], 0, 0, 0);
      }
    }
    int qw0 = qt * 64 + w * 16;
    if (kt * 128 + 127 > qw0) {  // causal mask (wave-uniform branch)
#pragma unroll
      for (int ni = 0; ni < 8; ni++) {
        int kv = kt * 128 + ni * 16 + l16;
#pragma unroll
        for (int r = 0; r < 4; r++)
          if (kv > qw0 + quad * 4 + r) accS[ni][r] = -1e30f;
      }
    }
    // online softmax
    float alpha[4];
#pragma unroll
    for (int r = 0; r < 4; r++) {
      float m = accS[0][r];
#pragma unroll
      for (int ni = 1; ni < 8; ni++) m = fmaxf(m, accS[ni][r]);
#pragma unroll
      for (int off = 1; off < 16; off <<= 1) m = fmaxf(m, __shfl_xor(m, off, 64));
      float mn = fmaxf(mrow[r], m);
      alpha[r] = __expf(mrow[r] - mn);
      mrow[r] = mn;
    }
    float sum[4] = {0.f, 0.f, 0.f, 0.f};
#pragma unroll
    for (int ni = 0; ni < 8; ni++) {
#pragma unroll
      for (int r = 0; r < 4; r++) {
        float p = __expf(accS[ni][r] - mrow[r]);
        sum[r] += p;
        sP[w][quad * 4 + r][ni * 16 + l16] = f2b(p);  // C-layout -> A-layout via LDS
      }
    }
#pragma unroll
    for (int r = 0; r < 4; r++) {
#pragma unroll
      for (int off = 1; off < 16; off <<= 1) sum[r] += __shfl_xor(sum[r], off, 64);
      lrow[r] = lrow[r] * alpha[r] + sum[r];
#pragma unroll
      for (int ni = 0; ni < 4; ni++) accO[ni][r] *= alpha[r];
    }
    __syncthreads();
    // O += P @ V
#pragma unroll
    for (int kk2 = 0; kk2 < 4; kk2++) {
      bf16x8 a = *(const bf16x8*)&sP[w][l16][kk2 * 32 + quad * 8];
#pragma unroll
      for (int ni = 0; ni < 4; ni++) {
        bf16x8 bb = *(const bf16x8*)&sV[ni * 16 + l16][kk2 * 32 + quad * 8];
        accO[ni] = __builtin_amdgcn_mfma_f32_16x16x32_bf16(a, bb, accO[ni], 0, 0, 0);
      }
    }
    __syncthreads();
  }
  u16* orow = ob + ((size_t)(b * S_ + qt * 64 + w * 16 + quad * 4)) * 1024 + h * 64;
#pragma unroll
  for (int r = 0; r < 4; r++) {
    float inv = 1.0f / lrow[r];
#pragma unroll
    for (int ni = 0; ni < 4; ni++)
      orow[(size_t)r * 1024 + ni * 16 + l16] = f2b(accO[ni][r] * inv);
  }
}

// ---------------- MFMA GEMM, global_load_lds staging + XOR swizzle ----------------
// C = A @ Bt^T. Tile BM_ x BN_, BK=64, 4 waves.
// 128x128: waves 2x2, acc 4x4. 64x128: waves 1x4, acc 4x2.
// KSPLIT>1: blockIdx.z = K-chunk; writes f32 partial at Cf + kz*M*ldC (no bias).
enum { M_PLAIN = 0, M_QKV = 1 };

template <int BM_, int BN_, int MODE, bool BIAS, bool GELU, bool RESID, bool WF32,
          bool WBF16, int KSPLIT>
__global__ __launch_bounds__(256, 2) void gemm_kernel(
    const u16* __restrict__ A, const u16* __restrict__ Bbase,
    const float* __restrict__ bias0, const float* __restrict__ bias1,
    const float* __restrict__ bias2, const float* __restrict__ resid,
    float* __restrict__ Cf, u16* __restrict__ Cb, u16* __restrict__ vTout,
    int M, int N, int K, int ldA, int ldB, int ldC) {
  constexpr int WAVES_M = (BM_ == 128) ? 2 : 1;
  constexpr int WAVES_N = 4 / WAVES_M;
  constexpr int WM = BM_ / WAVES_M;
  constexpr int WN = BN_ / WAVES_N;
  constexpr int MI = WM / 16;
  constexpr int NI = WN / 16;
  constexpr int ASZ = BM_ * 64;  // u16 elems

  int bn = blockIdx.x, bm = blockIdx.y, z = blockIdx.z;
  const u16* Bt = Bbase;
  const float* bias = bias0;
  u16* cb = Cb;
  if (MODE == M_QKV) {
    Bt = Bbase + (size_t)z * (1u << 20);
    bias = (z == 0) ? bias0 : (z == 1) ? bias1 : bias2;
    cb = Cb + (size_t)z * ((size_t)M_ROWS * 1024);
  }
  int kz = (KSPLIT > 1) ? z : 0;
  int k0beg = kz * (K / KSPLIT), k0end = k0beg + K / KSPLIT;

  int tid = threadIdx.x;
  int lane = tid & 63, w = tid >> 6;
  int l16 = lane & 15, quad = lane >> 4;
  int wm = (WAVES_M == 2) ? (w >> 1) : 0;
  int wn = (WAVES_M == 2) ? (w & 1) : w;
  int m0 = bm * BM_, n0 = bn * BN_;
  int rsub = lane >> 3, csw = lane & 7;

  __shared__ u16 smem[(BM_ + BN_) * 64];

  f32x4 acc[MI][NI];
#pragma unroll
  for (int i = 0; i < MI; i++)
#pragma unroll
    for (int j = 0; j < NI; j++) { f32x4 zv = {0.f, 0.f, 0.f, 0.f}; acc[i][j] = zv; }

  int rowA = w * (BM_ / 4) + rsub;
  int rowB = w * (BN_ / 4) + rsub;
  const u16* gA = A + (size_t)(m0 + rowA) * ldA + ((csw ^ (rowA & 7)) << 3);
  const u16* gB = Bt + (size_t)(n0 + rowB) * ldB + ((csw ^ (rowB & 7)) << 3);
  int swz = l16 & 7;

  for (int k0 = k0beg; k0 < k0end; k0 += 64) {
#pragma unroll
    for (int i = 0; i < BM_ / 32; i++)
      load16_lds(gA + (size_t)(i * 8) * ldA + k0, &smem[(w * (BM_ / 4) + i * 8) * 64]);
#pragma unroll
    for (int i = 0; i < BN_ / 32; i++)
      load16_lds(gB + (size_t)(i * 8) * ldB + k0, &smem[ASZ + (w * (BN_ / 4) + i * 8) * 64]);
    __syncthreads();
#pragma unroll
    for (int kk = 0; kk < 2; kk++) {
      bf16x8 af[MI], bfr[NI];
#pragma unroll
      for (int mi = 0; mi < MI; mi++)
        af[mi] = *(const bf16x8*)&smem[(wm * WM + mi * 16 + l16) * 64 +
                                       (((kk * 4 + quad) ^ swz) << 3)];
#pragma unroll
      for (int ni = 0; ni < NI; ni++)
        bfr[ni] = *(const bf16x8*)&smem[ASZ + (wn * WN + ni * 16 + l16) * 64 +
                                        (((kk * 4 + quad) ^ swz) << 3)];
#pragma unroll
      for (int mi = 0; mi < MI; mi++)
#pragma unroll
        for (int ni = 0; ni < NI; ni++)
          acc[mi][ni] = __builtin_amdgcn_mfma_f32_16x16x32_bf16(af[mi], bfr[ni],
                                                                acc[mi][ni], 0, 0, 0);
    }
    __syncthreads();
  }

  if (MODE == M_QKV && z == 2) {
    // V output: transpose tile through LDS (chunk-swizzled), write vT coalesced.
#pragma unroll
    for (int mi = 0; mi < MI; mi++) {
      int sl = wm * WM + mi * 16 + quad * 4;
#pragma unroll
      for (int ni = 0; ni < NI; ni++) {
        int dl = wn * WN + ni * 16 + l16;
        float bv = bias[n0 + dl];
        union { u16 h[4]; uint2 u; } pk;
#pragma unroll
        for (int r = 0; r < 4; r++) pk.h[r] = f2b(acc[mi][ni][r] + bv);
        int phys = ((((sl >> 3) ^ (dl & 7)) << 3) | (sl & 7));
        *(uint2*)&smem[dl * 128 + phys] = pk.u;
      }
    }
    __syncthreads();
    {
      int drow = tid >> 1;
      int b = m0 >> 10;
      int gcol = n0 + drow;
      u16* dst = vTout + ((size_t)((b * 16 + (gcol >> 6)) * 64 + (gcol & 63))) * 1024 +
                 (m0 & 1023);
#pragma unroll
      for (int i = 0; i < 8; i++) {
        int sc = (tid & 1) * 8 + i;
        int phys = sc ^ (drow & 7);
        *(uint4*)(dst + sc * 8) = *(const uint4*)&smem[drow * 128 + phys * 8];
      }
    }
    return;
  }

  float* cf = Cf;
  if (KSPLIT > 1) cf = Cf + (size_t)kz * ((size_t)M * ldC);
#pragma unroll
  for (int mi = 0; mi < MI; mi++)
#pragma unroll
    for (int ni = 0; ni < NI; ni++) {
      int col = n0 + wn * WN + ni * 16 + l16;
      float bv = BIAS ? bias[col] : 0.f;
#pragma unroll
      for (int r = 0; r < 4; r++) {
        int row = m0 + wm * WM + mi * 16 + quad * 4 + r;
        float v = acc[mi][ni][r] + bv;
        if (RESID) v += resid[(size_t)row * ldC + col];
        if (GELU) v = 0.5f * v * (1.f + erff(v * 0.70710678118f));
        if (WF32) cf[(size_t)row * ldC + col] = v;
        if (WBF16) cb[(size_t)row * ldC + col] = f2b(v);
      }
    }
}

// ---------------- split-K reduce: x = hf + b2 + sum_z part[z]; write xf + xb ------
__global__ void reduce4_kernel(const float* __restrict__ part, const float* __restrict__ hf,
                               const float* __restrict__ b2, float* __restrict__ xf,
                               u16* __restrict__ xb) {
  int idx = (blockIdx.x * 256 + threadIdx.x) * 4;  // 2M elems / 4 per thread
  const size_t NT = (size_t)M_ROWS * 1024;
  float4 a = *(const float4*)(hf + idx);
  float4 bb = *(const float4*)(b2 + (idx & 1023));
  a.x += bb.x; a.y += bb.y; a.z += bb.z; a.w += bb.w;
#pragma unroll
  for (int z = 0; z < 4; z++) {
    float4 p = *(const float4*)(part + (size_t)z * NT + idx);
    a.x += p.x; a.y += p.y; a.z += p.z; a.w += p.w;
  }
  *(float4*)(xf + idx) = a;
  union { u16 h[4]; uint2 u; } pk;
  pk.h[0] = f2b(a.x); pk.h[1] = f2b(a.y); pk.h[2] = f2b(a.z); pk.h[3] = f2b(a.w);
  *(uint2*)(xb + idx) = pk.u;
}

// ---------------- host-side orchestration ----------------
extern "C" void kernel_launch(void* const* d_in, const int* in_sizes, int n_in,
                              void* d_out, int out_size, void* d_ws, size_t ws_size,
                              hipStream_t stream) {
  const int*   tokens = (const int*)d_in[0];
  const float* emb = (const float*)d_in[1];
  const float* pos = (const float*)d_in[2];
  const float* Wq  = (const float*)d_in[3];
  const float* bq  = (const float*)d_in[4];
  const float* Wk  = (const float*)d_in[5];
  const float* bk  = (const float*)d_in[6];
  const float* Wv  = (const float*)d_in[7];
  const float* bv  = (const float*)d_in[8];
  const float* Wo  = (const float*)d_in[9];
  const float* W1  = (const float*)d_in[10];
  const float* b1  = (const float*)d_in[11];
  const float* W2  = (const float*)d_in[12];
  const float* b2  = (const float*)d_in[13];
  const float* Wr  = (const float*)d_in[14];
  const float* br  = (const float*)d_in[15];
  float* out = (float*)d_out;

  char* ws = (char*)d_ws;
  size_t off = 0;
  auto alloc = [&](size_t bytes) {
    char* p = ws + off;
    off += (bytes + 255) & ~(size_t)255;
    return p;
  };
  float* xf   = (float*)alloc((size_t)M_ROWS * 1024 * 4);
  float* hf   = (float*)alloc((size_t)M_ROWS * 1024 * 4);
  float* part = (float*)alloc((size_t)4 * M_ROWS * 1024 * 4);  // split-K partials
  u16*  xb    = (u16*)alloc((size_t)M_ROWS * 1024 * 2);
  u16*  hb    = (u16*)alloc((size_t)M_ROWS * 1024 * 2);
  u16*  qkb   = (u16*)alloc((size_t)2 * M_ROWS * 1024 * 2);  // q then k
  u16*  vT    = (u16*)alloc((size_t)M_ROWS * 1024 * 2);
  u16*  ob    = (u16*)alloc((size_t)M_ROWS * 1024 * 2);
  u16*  tmid  = (u16*)alloc((size_t)M_ROWS * DH_ * 2);
  u16*  Wt    = (u16*)alloc((size_t)8 * 12 * 1024 * 1024 * 2);  // all layers
  u16*  WrT   = (u16*)alloc((size_t)V_ * 1024 * 2);
  (void)ws_size; (void)in_sizes; (void)n_in; (void)out_size;

  embed_kernel<<<dim3(M_ROWS), 256, 0, stream>>>(tokens, emb, pos, xf, xb);
  convAllLayers_kernel<<<dim3(98560), 256, 0, stream>>>(Wq, Wk, Wv, Wo, W1, W2, Wr, Wt, WrT);

  for (int l = 0; l < L_; l++) {
    u16* slab = Wt + (size_t)l * (12u << 20);
    u16* WqT = slab;                        // [1024,1024] x3 (q,k,v)
    u16* WoT = slab + (3u << 20);
    u16* W1T = slab + (4u << 20);           // [4096,1024]
    u16* W2T = slab + (8u << 20);           // [1024,4096]

    // QKV projections (z=0:q, 1:k, 2:v written transposed into vT)
    gemm_kernel<128, 128, M_QKV, true, false, false, false, true, 1>
        <<<dim3(8, 16, 3), 256, 0, stream>>>(
        xb, WqT, bq + l * 1024, bk + l * 1024, bv + l * 1024, nullptr,
        nullptr, qkb, vT, M_ROWS, 1024, 1024, 1024, 1024, 1024);
    // fused flash attention
    flash_kernel<<<dim3(16, 32), 256, 0, stream>>>(qkb, qkb + (size_t)M_ROWS * 1024, vT, ob);
    // h = x + o @ Wo   (64x128 tiles -> 256 blocks)
    gemm_kernel<64, 128, M_PLAIN, false, false, true, true, true, 1>
        <<<dim3(8, 32), 256, 0, stream>>>(
        ob, WoT, nullptr, nullptr, nullptr, xf,
        hf, hb, nullptr, M_ROWS, 1024, 1024, 1024, 1024, 1024);
    // t = gelu(h @ W1 + b1)
    gemm_kernel<128, 128, M_PLAIN, true, true, false, false, true, 1>
        <<<dim3(32, 16), 256, 0, stream>>>(
        hb, W1T, b1 + l * DH_, nullptr, nullptr, nullptr,
        nullptr, tmid, nullptr, M_ROWS, DH_, 1024, 1024, 1024, DH_);
    // W2 split-K=4: partials
    gemm_kernel<128, 128, M_PLAIN, false, false, false, true, false, 4>
        <<<dim3(8, 16, 4), 256, 0, stream>>>(
        tmid, W2T, nullptr, nullptr, nullptr, nullptr,
        part, nullptr, nullptr, M_ROWS, 1024, DH_, DH_, DH_, 1024);
    // x = h + b2 + sum(partials)
    reduce4_kernel<<<dim3(2048), 256, 0, stream>>>(part, hf, b2 + l * 1024, xf, xb);
  }

  // logits = x @ Wr + br  (64x128 tiles -> 64 blocks)
  gemm_kernel<64, 128, M_PLAIN, true, false, false, true, false, 1>
      <<<dim3(2, 32), 256, 0, stream>>>(
      xb, WrT, br, nullptr, nullptr, nullptr,
      out, nullptr, nullptr, M_ROWS, V_, 1024, 1024, 1024, V_);
}